// Round 6
// baseline (1474.840 us; speedup 1.0000x reference)
//
#include <hip/hip_runtime.h>
#include <hip/hip_bf16.h>
#include <math.h>

typedef __hip_bfloat16 bf16;
typedef __attribute__((ext_vector_type(8))) short short8;   // 8 bf16 (4 VGPRs)
typedef __attribute__((ext_vector_type(4))) float floatx4;  // 4 fp32 acc

#define B_  32
#define H_  168
#define N_  512
#define P_  24
#define NF_ 4096
#define G4N 2048
#define M1  (B_*H_)        // 5376
#define NX  (M1*NF_)       // 22020096
#define TSTEPS (H_+P_)     // 192
#define NWG 64

// ---------------- fp32 -> bf16 convert (x) ----------------------------------
__global__ __launch_bounds__(256) void cvt_f32_bf16(const float* __restrict__ in,
                                                    bf16* __restrict__ out, int n4) {
  int i = blockIdx.x * 256 + threadIdx.x;
  if (i < n4) {
    float4 v = ((const float4*)in)[i];
    bf16 o[4] = {__float2bfloat16(v.x), __float2bfloat16(v.y),
                 __float2bfloat16(v.z), __float2bfloat16(v.w)};
    *(ulong1*)(out + (size_t)i * 4) = *(ulong1*)o;
  }
}

// ---------- tiled transpose + convert: out[C,R](bf16) = in[R,C](f32)^T ------
__global__ __launch_bounds__(256) void transpose_cvt(const float* __restrict__ in,
                                                     bf16* __restrict__ out,
                                                     int R, int C) {
  __shared__ float t[32][33];
  int bx = blockIdx.x, by = blockIdx.y;
  int tx = threadIdx.x, ty = threadIdx.y;
#pragma unroll
  for (int yy = 0; yy < 32; yy += 8)
    t[ty + yy][tx] = in[(size_t)(by * 32 + ty + yy) * C + bx * 32 + tx];
  __syncthreads();
#pragma unroll
  for (int yy = 0; yy < 32; yy += 8)
    out[(size_t)(bx * 32 + ty + yy) * R + by * 32 + tx] =
        __float2bfloat16(t[tx][ty + yy]);
}

// ---------- transpose + add + convert: out = (in1+in2)^T in bf16 ------------
__global__ __launch_bounds__(256) void transpose_add_cvt(const float* __restrict__ in1,
                                                         const float* __restrict__ in2,
                                                         bf16* __restrict__ out,
                                                         int R, int C) {
  __shared__ float t[32][33];
  int bx = blockIdx.x, by = blockIdx.y;
  int tx = threadIdx.x, ty = threadIdx.y;
#pragma unroll
  for (int yy = 0; yy < 32; yy += 8) {
    size_t idx = (size_t)(by * 32 + ty + yy) * C + bx * 32 + tx;
    t[ty + yy][tx] = in1[idx] + in2[idx];
  }
  __syncthreads();
#pragma unroll
  for (int yy = 0; yy < 32; yy += 8)
    out[(size_t)(bx * 32 + ty + yy) * R + by * 32 + tx] =
        __float2bfloat16(t[tx][ty + yy]);
}

// ---------------- C[M,N] = A[M,K] @ BT[N,K]^T (+bias) -----------------------
template <bool OUT_BF16>
__global__ __launch_bounds__(256) void gemm_bt(const bf16* __restrict__ A,
                                               const bf16* __restrict__ BT,
                                               const float* __restrict__ bias,
                                               void* __restrict__ Cout,
                                               int M, int N, int K, int permute) {
  __shared__ short As[128 * 40];
  __shared__ short Bs[128 * 40];
  int tid  = threadIdx.x;
  int wave = tid >> 6, lane = tid & 63;
  int wm = wave >> 1, wn = wave & 1;
  int quad = lane >> 4, l16 = lane & 15;
  int m0 = blockIdx.y * 128, n0 = blockIdx.x * 128;

  floatx4 acc[4][4];
#pragma unroll
  for (int i = 0; i < 4; i++)
#pragma unroll
    for (int j = 0; j < 4; j++) acc[i][j] = (floatx4){0.f, 0.f, 0.f, 0.f};

  int r0 = tid >> 2;
  int c0 = (tid & 3) * 8;

  for (int k0 = 0; k0 < K; k0 += 32) {
    short8 a0 = *(const short8*)(A  + (size_t)(m0 + r0)      * K + k0 + c0);
    short8 a1 = *(const short8*)(A  + (size_t)(m0 + r0 + 64) * K + k0 + c0);
    short8 b0 = *(const short8*)(BT + (size_t)(n0 + r0)      * K + k0 + c0);
    short8 b1 = *(const short8*)(BT + (size_t)(n0 + r0 + 64) * K + k0 + c0);
    __syncthreads();
    *(short8*)(&As[r0 * 40 + c0])        = a0;
    *(short8*)(&As[(r0 + 64) * 40 + c0]) = a1;
    *(short8*)(&Bs[r0 * 40 + c0])        = b0;
    *(short8*)(&Bs[(r0 + 64) * 40 + c0]) = b1;
    __syncthreads();
    short8 af[4], bfr[4];
#pragma unroll
    for (int i = 0; i < 4; i++)
      af[i] = *(const short8*)(&As[(wm * 64 + i * 16 + l16) * 40 + quad * 8]);
#pragma unroll
    for (int j = 0; j < 4; j++)
      bfr[j] = *(const short8*)(&Bs[(wn * 64 + j * 16 + l16) * 40 + quad * 8]);
#pragma unroll
    for (int i = 0; i < 4; i++)
#pragma unroll
      for (int j = 0; j < 4; j++)
        acc[i][j] = __builtin_amdgcn_mfma_f32_16x16x32_bf16(af[i], bfr[j],
                                                            acc[i][j], 0, 0, 0);
  }
#pragma unroll
  for (int i = 0; i < 4; i++) {
    int row = m0 + wm * 64 + i * 16 + quad * 4;
#pragma unroll
    for (int j = 0; j < 4; j++) {
      int col = n0 + wn * 64 + j * 16 + l16;
      float bv = bias ? bias[col] : 0.f;
#pragma unroll
      for (int r = 0; r < 4; r++) {
        int gr = row + r;
        int orow = permute ? (gr % H_) * B_ + gr / H_ : gr;
        float v = acc[i][j][r] + bv;
        if (OUT_BF16)
          ((bf16*)Cout)[(size_t)orow * N + col] = __float2bfloat16(v);
        else
          ((float*)Cout)[(size_t)orow * N + col] = v;
      }
    }
  }
}

// ---------------- persistent LSTM recurrence (all 192 steps) ----------------
// 64 WGs x 256 thr. WG g owns n in [g*8,g*8+8) -> 32 gate cols {gate*512+n}.
// Weights LDS-resident. c in registers. h exchanged via relaxed agent-scope
// atomics (coherent at Infinity Cache; no per-step L2 fences).
// h staged once per WG into LDS (cooperative 8B loads); A-fragments from LDS.
// Two-line barrier: fetch_add arrivals on bar[t], last arriver writes flag[t],
// others poll flag[t] only (read-only line -> no RMW contention).
__global__ __launch_bounds__(256) void lstm_persist(
    const bf16* __restrict__ rkT,   // [2048,512] recurrent (encoder)
    const bf16* __restrict__ wcT,   // [2048,512] k+rk (decoder)
    const float* __restrict__ bvec, // [2048]
    const float* __restrict__ xk,   // [H*B, 2048] fp32, rows t*B+b
    bf16* __restrict__ h0, bf16* __restrict__ h1,  // [32,512] dbuf, h0 zeroed
    bf16* __restrict__ preds,       // [B,P,N]
    unsigned* __restrict__ bar,     // [TSTEPS] zeroed
    unsigned* __restrict__ flag) {  // [TSTEPS] zeroed
  __shared__ short Wenc[32][520];
  __shared__ short Wdec[32][520];
  __shared__ short As[32][520];     // staged h: 512 shorts + 8 pad per row
  __shared__ float zs[32][33];
  __shared__ bf16  hstage[32][8];

  int tid  = threadIdx.x;
  int wave = tid >> 6, lane = tid & 63;
  int tm = wave >> 1, tn = wave & 1;
  int quad = lane >> 4, l16 = lane & 15;
  int n0 = blockIdx.x * 8;
  int lc   = tn * 16 + l16;                     // local col 0..31
  int gcol = ((lc >> 3) << 9) + n0 + (lc & 7);  // gate*512 + n
  int brow = tm * 16 + quad * 4;

  for (int idx = tid; idx < 32 * 64; idx += 256) {
    int r = idx >> 6, ck = (idx & 63) << 3;
    int grow = ((r >> 3) << 9) + n0 + (r & 7);
    *(short8*)&Wenc[r][ck] = *(const short8*)(rkT + (size_t)grow * 512 + ck);
    *(short8*)&Wdec[r][ck] = *(const short8*)(wcT + (size_t)grow * 512 + ck);
  }
  float bias_r = bvec[gcol];
  int b = tid >> 3, j = tid & 7;
  int nn = n0 + j;
  float c_reg = 0.f;

  // prefetch xk for t=0
  float xkv[4];
  {
    const float* xp = xk + (size_t)brow * G4N + gcol;
#pragma unroll
    for (int r = 0; r < 4; ++r) xkv[r] = xp[(size_t)r * G4N];
  }
  __syncthreads();

  bf16* hb[2] = {h0, h1};
  for (int t = 0; t < TSTEPS; ++t) {
    const bf16* h_in = hb[t & 1];
    bf16* h_out = hb[(t + 1) & 1];
    const short(*Ws)[520] = (t < H_) ? Wenc : Wdec;

    // ---- stage h_in -> LDS (4096 x 8B agent atomic loads, cooperative) ----
    {
      const unsigned long long* hsrc = (const unsigned long long*)h_in;
#pragma unroll
      for (int i = 0; i < 16; ++i) {
        int idx = tid + i * 256;     // 0..4095
        int row = idx >> 7;          // 128 x 8B chunks per 512-short row
        int ck  = idx & 127;
        unsigned long long v = __hip_atomic_load(hsrc + idx, __ATOMIC_RELAXED,
                                                 __HIP_MEMORY_SCOPE_AGENT);
        *(unsigned long long*)&As[row][ck << 2] = v;
      }
    }
    __syncthreads();

    floatx4 acc0 = (floatx4){0.f, 0.f, 0.f, 0.f};
    floatx4 acc1 = (floatx4){0.f, 0.f, 0.f, 0.f};
    const short* ap = &As[tm * 16 + l16][quad * 8];
    const short* bp = &Ws[lc][quad * 8];
#pragma unroll
    for (int k0 = 0; k0 < 512; k0 += 64) {
      short8 av0 = *(const short8*)(ap + k0);
      short8 av1 = *(const short8*)(ap + k0 + 32);
      short8 bv0 = *(const short8*)(bp + k0);
      short8 bv1 = *(const short8*)(bp + k0 + 32);
      acc0 = __builtin_amdgcn_mfma_f32_16x16x32_bf16(av0, bv0, acc0, 0, 0, 0);
      acc1 = __builtin_amdgcn_mfma_f32_16x16x32_bf16(av1, bv1, acc1, 0, 0, 0);
    }
    floatx4 acc = acc0 + acc1;
#pragma unroll
    for (int r = 0; r < 4; ++r)
      zs[brow + r][lc] = acc[r] + bias_r + xkv[r];

    // prefetch next step's xk (hidden behind barrier wait)
    float xn[4] = {0.f, 0.f, 0.f, 0.f};
    if (t + 1 < H_) {
      const float* xp = xk + (size_t)((t + 1) * B_ + brow) * G4N + gcol;
#pragma unroll
      for (int r = 0; r < 4; ++r) xn[r] = xp[(size_t)r * G4N];
    }
    __syncthreads();

    // ---- gates ----
    float zi = zs[b][j], zf = zs[b][8 + j], zg = zs[b][16 + j], zo = zs[b][24 + j];
    float ig = 1.f / (1.f + __expf(-zi));
    float fg = 1.f / (1.f + __expf(-zf));
    float gg = tanhf(zg);
    float og = 1.f / (1.f + __expf(-zo));
    c_reg = fg * c_reg + ig * gg;
    float hn = og * tanhf(c_reg);
    hstage[b][j] = __float2bfloat16(hn);
    if (t >= H_)
      preds[(size_t)b * (P_ * N_) + (t - H_) * N_ + nn] = __float2bfloat16(hn);
    __syncthreads();

    // ---- packed h_out stores: 64 threads x 8B ----
    if (tid < 64) {
      int bb = tid >> 1, f4 = (tid & 1) * 4;
      unsigned long long v = *(const unsigned long long*)&hstage[bb][f4];
      __hip_atomic_store((unsigned long long*)(h_out + bb * 512 + n0 + f4), v,
                         __ATOMIC_RELAXED, __HIP_MEMORY_SCOPE_AGENT);
    }
    // drains each wave's outstanding stores (vmcnt) before s_barrier
    __syncthreads();

    // ---- two-line grid barrier ----
    if (tid == 0) {
      unsigned old = __hip_atomic_fetch_add(&bar[t], 1u, __ATOMIC_RELAXED,
                                            __HIP_MEMORY_SCOPE_AGENT);
      if (old == NWG - 1) {
        __hip_atomic_store(&flag[t], 1u, __ATOMIC_RELAXED,
                           __HIP_MEMORY_SCOPE_AGENT);
      } else {
        while (!__hip_atomic_load(&flag[t], __ATOMIC_RELAXED,
                                  __HIP_MEMORY_SCOPE_AGENT))
          __builtin_amdgcn_s_sleep(2);
      }
    }
    __builtin_amdgcn_fence(__ATOMIC_ACQUIRE, "workgroup");
    __syncthreads();
#pragma unroll
    for (int r = 0; r < 4; ++r) xkv[r] = xn[r];
  }
}

extern "C" void kernel_launch(void* const* d_in, const int* in_sizes, int n_in,
                              void* d_out, int out_size, void* d_ws, size_t ws_size,
                              hipStream_t stream) {
  const float* x       = (const float*)d_in[0];
  const float* conv_w  = (const float*)d_in[1];
  const float* conv_b  = (const float*)d_in[2];
  const float* lstm_k  = (const float*)d_in[3];
  const float* lstm_rk = (const float*)d_in[4];
  const float* lstm_b  = (const float*)d_in[5];
  const float* dense_w = (const float*)d_in[6];
  const float* dense_b = (const float*)d_in[7];
  float* out = (float*)d_out;

  char* p = (char*)d_ws;
  auto carve = [&](size_t bytes) {
    char* r = p;
    p += (bytes + 255) & ~(size_t)255;
    return r;
  };
  bf16*  xb    = (bf16*)carve((size_t)NX * 2);
  bf16*  xr    = (bf16*)carve((size_t)M1 * N_ * 2);    // rows t*B+b
  float* xk    = (float*)carve((size_t)M1 * G4N * 4);  // rows t*B+b
  bf16*  cwT   = (bf16*)carve((size_t)N_ * NF_ * 2);
  bf16*  kT    = (bf16*)carve((size_t)G4N * N_ * 2);
  bf16*  rkT   = (bf16*)carve((size_t)G4N * N_ * 2);
  bf16*  wcT   = (bf16*)carve((size_t)G4N * N_ * 2);
  bf16*  dwT   = (bf16*)carve((size_t)N_ * N_ * 2);
  bf16*  preds = (bf16*)carve((size_t)B_ * P_ * N_ * 2);
  bf16*  hA    = (bf16*)carve((size_t)B_ * N_ * 2);
  bf16*  hB    = (bf16*)carve((size_t)B_ * N_ * 2);
  unsigned* bar  = (unsigned*)carve((size_t)TSTEPS * 4);
  unsigned* flag = (unsigned*)carve((size_t)TSTEPS * 4);

  cvt_f32_bf16<<<(NX / 4 + 255) / 256, 256, 0, stream>>>(x, xb, NX / 4);
  dim3 tb(32, 8);
  transpose_cvt<<<dim3(N_ / 32, NF_ / 32), tb, 0, stream>>>(conv_w, cwT, NF_, N_);
  transpose_cvt<<<dim3(G4N / 32, N_ / 32), tb, 0, stream>>>(lstm_k, kT, N_, G4N);
  transpose_cvt<<<dim3(G4N / 32, N_ / 32), tb, 0, stream>>>(lstm_rk, rkT, N_, G4N);
  transpose_add_cvt<<<dim3(G4N / 32, N_ / 32), tb, 0, stream>>>(lstm_k, lstm_rk,
                                                                wcT, N_, G4N);
  transpose_cvt<<<dim3(N_ / 32, N_ / 32), tb, 0, stream>>>(dense_w, dwT, N_, N_);
  hipMemsetAsync(hA, 0, (size_t)B_ * N_ * 2, stream);
  hipMemsetAsync(bar, 0, (size_t)TSTEPS * 4, stream);
  hipMemsetAsync(flag, 0, (size_t)TSTEPS * 4, stream);

  // xr = x @ conv_w + conv_b, rows permuted (b*H+t) -> (t*B+b)
  gemm_bt<true><<<dim3(N_ / 128, M1 / 128), 256, 0, stream>>>(xb, cwT, conv_b, xr,
                                                              M1, N_, NF_, 1);
  // xk = xr @ lstm_k -> fp32 (row order preserved: t*B+b)
  gemm_bt<false><<<dim3(G4N / 128, M1 / 128), 256, 0, stream>>>(xr, kT, nullptr,
                                                                xk, M1, G4N, N_, 0);

  lstm_persist<<<NWG, 256, 0, stream>>>(rkT, wcT, lstm_b, xk, hA, hB, preds,
                                        bar, flag);

  // out = preds @ dense_w + dense_b
  gemm_bt<false><<<dim3(N_ / 128, (B_ * P_) / 128), 256, 0, stream>>>(
      preds, dwT, dense_b, out, B_ * P_, N_, N_, 0);
}

// Round 7
// 1066.222 us; speedup vs baseline: 1.3832x; 1.3832x over previous
//
#include <hip/hip_runtime.h>
#include <hip/hip_bf16.h>
#include <math.h>

typedef __hip_bfloat16 bf16;
typedef __attribute__((ext_vector_type(8))) short short8;   // 8 bf16 (4 VGPRs)
typedef __attribute__((ext_vector_type(4))) float floatx4;  // 4 fp32 acc

#define B_  32
#define H_  168
#define N_  512
#define P_  24
#define NF_ 4096
#define G4N 2048
#define M1  (B_*H_)        // 5376
#define NX  (M1*NF_)       // 22020096
#define TSTEPS (H_+P_)     // 192
#define NWG 64
#define HSZ (B_*N_)        // one h buffer: 16384 bf16 = 32 KB

// ---------------- fp32 -> bf16 convert (x) ----------------------------------
__global__ __launch_bounds__(256) void cvt_f32_bf16(const float* __restrict__ in,
                                                    bf16* __restrict__ out, int n4) {
  int i = blockIdx.x * 256 + threadIdx.x;
  if (i < n4) {
    float4 v = ((const float4*)in)[i];
    bf16 o[4] = {__float2bfloat16(v.x), __float2bfloat16(v.y),
                 __float2bfloat16(v.z), __float2bfloat16(v.w)};
    *(ulong1*)(out + (size_t)i * 4) = *(ulong1*)o;
  }
}

// ---------- tiled transpose + convert: out[C,R](bf16) = in[R,C](f32)^T ------
__global__ __launch_bounds__(256) void transpose_cvt(const float* __restrict__ in,
                                                     bf16* __restrict__ out,
                                                     int R, int C) {
  __shared__ float t[32][33];
  int bx = blockIdx.x, by = blockIdx.y;
  int tx = threadIdx.x, ty = threadIdx.y;
#pragma unroll
  for (int yy = 0; yy < 32; yy += 8)
    t[ty + yy][tx] = in[(size_t)(by * 32 + ty + yy) * C + bx * 32 + tx];
  __syncthreads();
#pragma unroll
  for (int yy = 0; yy < 32; yy += 8)
    out[(size_t)(bx * 32 + ty + yy) * R + by * 32 + tx] =
        __float2bfloat16(t[tx][ty + yy]);
}

// ---------- transpose + add + convert: out = (in1+in2)^T in bf16 ------------
__global__ __launch_bounds__(256) void transpose_add_cvt(const float* __restrict__ in1,
                                                         const float* __restrict__ in2,
                                                         bf16* __restrict__ out,
                                                         int R, int C) {
  __shared__ float t[32][33];
  int bx = blockIdx.x, by = blockIdx.y;
  int tx = threadIdx.x, ty = threadIdx.y;
#pragma unroll
  for (int yy = 0; yy < 32; yy += 8) {
    size_t idx = (size_t)(by * 32 + ty + yy) * C + bx * 32 + tx;
    t[ty + yy][tx] = in1[idx] + in2[idx];
  }
  __syncthreads();
#pragma unroll
  for (int yy = 0; yy < 32; yy += 8)
    out[(size_t)(bx * 32 + ty + yy) * R + by * 32 + tx] =
        __float2bfloat16(t[tx][ty + yy]);
}

// ---------------- C[M,N] = A[M,K] @ BT[N,K]^T (+bias) -----------------------
template <bool OUT_BF16>
__global__ __launch_bounds__(256) void gemm_bt(const bf16* __restrict__ A,
                                               const bf16* __restrict__ BT,
                                               const float* __restrict__ bias,
                                               void* __restrict__ Cout,
                                               int M, int N, int K, int permute) {
  __shared__ short As[128 * 40];
  __shared__ short Bs[128 * 40];
  int tid  = threadIdx.x;
  int wave = tid >> 6, lane = tid & 63;
  int wm = wave >> 1, wn = wave & 1;
  int quad = lane >> 4, l16 = lane & 15;
  int m0 = blockIdx.y * 128, n0 = blockIdx.x * 128;

  floatx4 acc[4][4];
#pragma unroll
  for (int i = 0; i < 4; i++)
#pragma unroll
    for (int j = 0; j < 4; j++) acc[i][j] = (floatx4){0.f, 0.f, 0.f, 0.f};

  int r0 = tid >> 2;
  int c0 = (tid & 3) * 8;

  for (int k0 = 0; k0 < K; k0 += 32) {
    short8 a0 = *(const short8*)(A  + (size_t)(m0 + r0)      * K + k0 + c0);
    short8 a1 = *(const short8*)(A  + (size_t)(m0 + r0 + 64) * K + k0 + c0);
    short8 b0 = *(const short8*)(BT + (size_t)(n0 + r0)      * K + k0 + c0);
    short8 b1 = *(const short8*)(BT + (size_t)(n0 + r0 + 64) * K + k0 + c0);
    __syncthreads();
    *(short8*)(&As[r0 * 40 + c0])        = a0;
    *(short8*)(&As[(r0 + 64) * 40 + c0]) = a1;
    *(short8*)(&Bs[r0 * 40 + c0])        = b0;
    *(short8*)(&Bs[(r0 + 64) * 40 + c0]) = b1;
    __syncthreads();
    short8 af[4], bfr[4];
#pragma unroll
    for (int i = 0; i < 4; i++)
      af[i] = *(const short8*)(&As[(wm * 64 + i * 16 + l16) * 40 + quad * 8]);
#pragma unroll
    for (int j = 0; j < 4; j++)
      bfr[j] = *(const short8*)(&Bs[(wn * 64 + j * 16 + l16) * 40 + quad * 8]);
#pragma unroll
    for (int i = 0; i < 4; i++)
#pragma unroll
      for (int j = 0; j < 4; j++)
        acc[i][j] = __builtin_amdgcn_mfma_f32_16x16x32_bf16(af[i], bfr[j],
                                                            acc[i][j], 0, 0, 0);
  }
#pragma unroll
  for (int i = 0; i < 4; i++) {
    int row = m0 + wm * 64 + i * 16 + quad * 4;
#pragma unroll
    for (int j = 0; j < 4; j++) {
      int col = n0 + wn * 64 + j * 16 + l16;
      float bv = bias ? bias[col] : 0.f;
#pragma unroll
      for (int r = 0; r < 4; r++) {
        int gr = row + r;
        int orow = permute ? (gr % H_) * B_ + gr / H_ : gr;
        float v = acc[i][j][r] + bv;
        if (OUT_BF16)
          ((bf16*)Cout)[(size_t)orow * N + col] = __float2bfloat16(v);
        else
          ((float*)Cout)[(size_t)orow * N + col] = v;
      }
    }
  }
}

// ---------------- persistent LSTM recurrence (all 192 steps) ----------------
// 64 WGs x 256 thr. WG g owns n in [g*8,g*8+8) -> 32 gate cols {gate*512+n}.
// Weights LDS-resident. c in registers.
// h ring buffer: step t writes hring[t+1] (FRESH addresses every step), so
// consumers use NORMAL cached loads (L2-shared within an XCD, no staleness
// possible) while producers store via relaxed agent-scope atomics (ack at
// the coherent Infinity Cache before barrier arrival). Flag polling stays
// agent-scope (a cached poll would spin on a stale 0 forever).
__global__ __launch_bounds__(256) void lstm_persist(
    const bf16* __restrict__ rkT,   // [2048,512] recurrent (encoder)
    const bf16* __restrict__ wcT,   // [2048,512] k+rk (decoder)
    const float* __restrict__ bvec, // [2048]
    const float* __restrict__ xk,   // [H*B, 2048] fp32, rows t*B+b
    bf16* __restrict__ hring,       // [(TSTEPS+1)*B*N]; buffer 0 zeroed
    bf16* __restrict__ preds,       // [B,P,N]
    unsigned* __restrict__ bar,     // [TSTEPS] zeroed
    unsigned* __restrict__ flag) {  // [TSTEPS] zeroed
  __shared__ short Wenc[32][520];
  __shared__ short Wdec[32][520];
  __shared__ float zs[32][33];
  __shared__ bf16  hstage[32][8];

  int tid  = threadIdx.x;
  int wave = tid >> 6, lane = tid & 63;
  int tm = wave >> 1, tn = wave & 1;
  int quad = lane >> 4, l16 = lane & 15;
  int n0 = blockIdx.x * 8;
  int lc   = tn * 16 + l16;                     // local col 0..31
  int gcol = ((lc >> 3) << 9) + n0 + (lc & 7);  // gate*512 + n
  int brow = tm * 16 + quad * 4;

  for (int idx = tid; idx < 32 * 64; idx += 256) {
    int r = idx >> 6, ck = (idx & 63) << 3;
    int grow = ((r >> 3) << 9) + n0 + (r & 7);
    *(short8*)&Wenc[r][ck] = *(const short8*)(rkT + (size_t)grow * 512 + ck);
    *(short8*)&Wdec[r][ck] = *(const short8*)(wcT + (size_t)grow * 512 + ck);
  }
  float bias_r = bvec[gcol];
  int b = tid >> 3, j = tid & 7;
  int nn = n0 + j;
  float c_reg = 0.f;

  // prefetch xk for t=0
  float xkv[4];
  {
    const float* xp = xk + (size_t)brow * G4N + gcol;
#pragma unroll
    for (int r = 0; r < 4; ++r) xkv[r] = xp[(size_t)r * G4N];
  }
  __syncthreads();

  for (int t = 0; t < TSTEPS; ++t) {
    const bf16* h_in = hring + (size_t)t * HSZ;        // fresh address: cacheable
    bf16*       h_out = hring + (size_t)(t + 1) * HSZ;
    const short(*Ws)[520] = (t < H_) ? Wenc : Wdec;

    floatx4 acc0 = (floatx4){0.f, 0.f, 0.f, 0.f};
    floatx4 acc1 = (floatx4){0.f, 0.f, 0.f, 0.f};
    const bf16*  ap = h_in + (size_t)(tm * 16 + l16) * 512 + quad * 8;
    const short* bp = &Ws[lc][quad * 8];
#pragma unroll
    for (int k0 = 0; k0 < 512; k0 += 64) {
      short8 av0 = *(const short8*)(ap + k0);         // normal load: L2-shared
      short8 av1 = *(const short8*)(ap + k0 + 32);
      short8 bv0 = *(const short8*)(bp + k0);
      short8 bv1 = *(const short8*)(bp + k0 + 32);
      acc0 = __builtin_amdgcn_mfma_f32_16x16x32_bf16(av0, bv0, acc0, 0, 0, 0);
      acc1 = __builtin_amdgcn_mfma_f32_16x16x32_bf16(av1, bv1, acc1, 0, 0, 0);
    }
    floatx4 acc = acc0 + acc1;
#pragma unroll
    for (int r = 0; r < 4; ++r)
      zs[brow + r][lc] = acc[r] + bias_r + xkv[r];

    // prefetch next step's xk (consumed after the barrier)
    float xn[4] = {0.f, 0.f, 0.f, 0.f};
    if (t + 1 < H_) {
      const float* xp = xk + (size_t)((t + 1) * B_ + brow) * G4N + gcol;
#pragma unroll
      for (int r = 0; r < 4; ++r) xn[r] = xp[(size_t)r * G4N];
    }
    __syncthreads();

    // ---- gates ----
    float zi = zs[b][j], zf = zs[b][8 + j], zg = zs[b][16 + j], zo = zs[b][24 + j];
    float ig = 1.f / (1.f + __expf(-zi));
    float fg = 1.f / (1.f + __expf(-zf));
    float gg = tanhf(zg);
    float og = 1.f / (1.f + __expf(-zo));
    c_reg = fg * c_reg + ig * gg;
    float hn = og * tanhf(c_reg);
    hstage[b][j] = __float2bfloat16(hn);
    if (t >= H_)
      preds[(size_t)b * (P_ * N_) + (t - H_) * N_ + nn] = __float2bfloat16(hn);
    __syncthreads();

    // ---- packed h_out stores: 64 threads x 8B, L2-bypass to coherent L3 ----
    if (tid < 64) {
      int bb = tid >> 1, f4 = (tid & 1) * 4;
      unsigned long long v = *(const unsigned long long*)&hstage[bb][f4];
      __hip_atomic_store((unsigned long long*)(h_out + bb * 512 + n0 + f4), v,
                         __ATOMIC_RELAXED, __HIP_MEMORY_SCOPE_AGENT);
    }
    // syncthreads drains each wave's vmcnt: stores ack'd before arrival
    __syncthreads();

    // ---- two-line grid barrier ----
    if (tid == 0) {
      unsigned old = __hip_atomic_fetch_add(&bar[t], 1u, __ATOMIC_RELAXED,
                                            __HIP_MEMORY_SCOPE_AGENT);
      if (old == NWG - 1) {
        __hip_atomic_store(&flag[t], 1u, __ATOMIC_RELAXED,
                           __HIP_MEMORY_SCOPE_AGENT);
      } else {
        while (!__hip_atomic_load(&flag[t], __ATOMIC_RELAXED,
                                  __HIP_MEMORY_SCOPE_AGENT))
          __builtin_amdgcn_s_sleep(1);
      }
    }
    __builtin_amdgcn_fence(__ATOMIC_ACQUIRE, "workgroup");
    __syncthreads();
#pragma unroll
    for (int r = 0; r < 4; ++r) xkv[r] = xn[r];
  }
}

extern "C" void kernel_launch(void* const* d_in, const int* in_sizes, int n_in,
                              void* d_out, int out_size, void* d_ws, size_t ws_size,
                              hipStream_t stream) {
  const float* x       = (const float*)d_in[0];
  const float* conv_w  = (const float*)d_in[1];
  const float* conv_b  = (const float*)d_in[2];
  const float* lstm_k  = (const float*)d_in[3];
  const float* lstm_rk = (const float*)d_in[4];
  const float* lstm_b  = (const float*)d_in[5];
  const float* dense_w = (const float*)d_in[6];
  const float* dense_b = (const float*)d_in[7];
  float* out = (float*)d_out;

  char* p = (char*)d_ws;
  auto carve = [&](size_t bytes) {
    char* r = p;
    p += (bytes + 255) & ~(size_t)255;
    return r;
  };
  bf16*  xb    = (bf16*)carve((size_t)NX * 2);
  bf16*  xr    = (bf16*)carve((size_t)M1 * N_ * 2);    // rows t*B+b
  float* xk    = (float*)carve((size_t)M1 * G4N * 4);  // rows t*B+b
  bf16*  cwT   = (bf16*)carve((size_t)N_ * NF_ * 2);
  bf16*  kT    = (bf16*)carve((size_t)G4N * N_ * 2);
  bf16*  rkT   = (bf16*)carve((size_t)G4N * N_ * 2);
  bf16*  wcT   = (bf16*)carve((size_t)G4N * N_ * 2);
  bf16*  dwT   = (bf16*)carve((size_t)N_ * N_ * 2);
  bf16*  preds = (bf16*)carve((size_t)B_ * P_ * N_ * 2);
  bf16*  hring = (bf16*)carve((size_t)(TSTEPS + 1) * HSZ * 2);  // 6.2 MB
  unsigned* bar  = (unsigned*)carve((size_t)TSTEPS * 4);
  unsigned* flag = (unsigned*)carve((size_t)TSTEPS * 4);

  cvt_f32_bf16<<<(NX / 4 + 255) / 256, 256, 0, stream>>>(x, xb, NX / 4);
  dim3 tb(32, 8);
  transpose_cvt<<<dim3(N_ / 32, NF_ / 32), tb, 0, stream>>>(conv_w, cwT, NF_, N_);
  transpose_cvt<<<dim3(G4N / 32, N_ / 32), tb, 0, stream>>>(lstm_k, kT, N_, G4N);
  transpose_cvt<<<dim3(G4N / 32, N_ / 32), tb, 0, stream>>>(lstm_rk, rkT, N_, G4N);
  transpose_add_cvt<<<dim3(G4N / 32, N_ / 32), tb, 0, stream>>>(lstm_k, lstm_rk,
                                                                wcT, N_, G4N);
  transpose_cvt<<<dim3(N_ / 32, N_ / 32), tb, 0, stream>>>(dense_w, dwT, N_, N_);
  hipMemsetAsync(hring, 0, (size_t)HSZ * 2, stream);   // h[0] = 0
  hipMemsetAsync(bar, 0, (size_t)TSTEPS * 4, stream);
  hipMemsetAsync(flag, 0, (size_t)TSTEPS * 4, stream);

  // xr = x @ conv_w + conv_b, rows permuted (b*H+t) -> (t*B+b)
  gemm_bt<true><<<dim3(N_ / 128, M1 / 128), 256, 0, stream>>>(xb, cwT, conv_b, xr,
                                                              M1, N_, NF_, 1);
  // xk = xr @ lstm_k -> fp32 (row order preserved: t*B+b)
  gemm_bt<false><<<dim3(G4N / 128, M1 / 128), 256, 0, stream>>>(xr, kT, nullptr,
                                                                xk, M1, G4N, N_, 0);

  lstm_persist<<<NWG, 256, 0, stream>>>(rkT, wcT, lstm_b, xk, hring, preds,
                                        bar, flag);

  // out = preds @ dense_w + dense_b
  gemm_bt<false><<<dim3(N_ / 128, (B_ * P_) / 128), 256, 0, stream>>>(
      preds, dwT, dense_b, out, B_ * P_, N_, N_, 0);
}